// Round 2
// baseline (856.899 us; speedup 1.0000x reference)
//
#include <hip/hip_runtime.h>
#include <math.h>

// ---------------- problem constants ----------------
#define B_SZ    16
#define N_ROWS  8192
#define D       768
#define EPS_LN  1e-6f
#define EPS_POOL 1e-6f

#define ROWS_PER_BLOCK 64
#define ROWS_PER_WAVE  16
#define BLOCKS_PER_B   (N_ROWS / ROWS_PER_BLOCK)   // 128
#define NBLK_PASS      (B_SZ * BLOCKS_PER_B)       // 2048

// ---------------- workspace layout (float offsets) ----------------
// total = 430144 floats = 1.72 MB
#define WS_COLSUM   0                      // B*D   = 12288 (zeroed)
#define WS_OUTACC   (WS_COLSUM + B_SZ*D)   // B*D   = 12288 (zeroed)
#define WS_GMIN     (WS_OUTACC + B_SZ*D)   // 1 uint (init +inf)
#define WS_MXSUM    (WS_GMIN + 32)         // 2*B   = 32
#define WS_MU       (WS_MXSUM + 2*B_SZ)    // B*N   = 131072
#define WS_RSTD     (WS_MU + B_SZ*N_ROWS)  // B*N
#define WS_R        (WS_RSTD + B_SZ*N_ROWS)// B*D
#define WS_LOGITS   (WS_R + B_SZ*D)        // B*N

// ---------------- small helpers ----------------
__device__ __forceinline__ float hsum4(float4 v)  { return (v.x + v.y) + (v.z + v.w); }
__device__ __forceinline__ float hsumsq4(float4 v){ return (v.x*v.x + v.y*v.y) + (v.z*v.z + v.w*v.w); }
__device__ __forceinline__ float dot4(float4 a, float4 b) {
    return (a.x*b.x + a.y*b.y) + (a.z*b.z + a.w*b.w);
}
__device__ __forceinline__ float4 kv4(float4 xv, float4 wv, float4 bv, float mu, float rstd) {
    return make_float4((xv.x-mu)*rstd*wv.x + bv.x,
                       (xv.y-mu)*rstd*wv.y + bv.y,
                       (xv.z-mu)*rstd*wv.z + bv.z,
                       (xv.w-mu)*rstd*wv.w + bv.w);
}
__device__ __forceinline__ float hmin4(float4 v) { return fminf(fminf(v.x, v.y), fminf(v.z, v.w)); }

// float atomic-min via signed-min / unsigned-max trick (init must be +inf bits)
__device__ __forceinline__ void atomicMinFloat(unsigned int* addr, float val) {
    if (val >= 0.0f) atomicMin((int*)addr, __float_as_int(val));
    else             atomicMax(addr, __float_as_uint(val));
}

// ---------------- K0: init accumulators ----------------
__global__ __launch_bounds__(256) void k0_init(float* __restrict__ ws) {
    int i = blockIdx.x * 256 + threadIdx.x;
    if (i < 2 * B_SZ * D) ws[i] = 0.0f;          // colsum + outacc
    if (i == 0) ((unsigned int*)ws)[WS_GMIN] = 0x7F800000u;  // +inf
}

// ---------------- K1: row LN stats + column sums + global kv min ----------------
__global__ __launch_bounds__(256) void k1_stats(const float* __restrict__ x,
                                                const float* __restrict__ lnw,
                                                const float* __restrict__ lnb,
                                                float* __restrict__ ws) {
    __shared__ float lds[4][D];
    __shared__ float wvmin[4];
    const int tid  = threadIdx.x;
    const int lane = tid & 63;
    const int wv   = tid >> 6;
    const int b    = blockIdx.x / BLOCKS_PER_B;
    const int chunk= blockIdx.x % BLOCKS_PER_B;
    const int n0   = chunk * ROWS_PER_BLOCK + wv * ROWS_PER_WAVE;

    const float4 w0 = *(const float4*)(lnw + 4*lane);
    const float4 w1 = *(const float4*)(lnw + 4*lane + 256);
    const float4 w2 = *(const float4*)(lnw + 4*lane + 512);
    const float4 c0 = *(const float4*)(lnb + 4*lane);
    const float4 c1 = *(const float4*)(lnb + 4*lane + 256);
    const float4 c2 = *(const float4*)(lnb + 4*lane + 512);

    float cs[12];
    #pragma unroll
    for (int i = 0; i < 12; ++i) cs[i] = 0.0f;
    float kvmin = INFINITY;

    float* mu_arr   = ws + WS_MU   + (size_t)b * N_ROWS;
    float* rstd_arr = ws + WS_RSTD + (size_t)b * N_ROWS;

    for (int i = 0; i < ROWS_PER_WAVE; ++i) {
        const int n = n0 + i;
        const float* row = x + ((size_t)b * N_ROWS + n) * D;
        const float4 x0 = *(const float4*)(row + 4*lane);
        const float4 x1 = *(const float4*)(row + 4*lane + 256);
        const float4 x2 = *(const float4*)(row + 4*lane + 512);

        float s  = hsum4(x0)   + hsum4(x1)   + hsum4(x2);
        float ss = hsumsq4(x0) + hsumsq4(x1) + hsumsq4(x2);
        #pragma unroll
        for (int off = 32; off; off >>= 1) {
            s  += __shfl_xor(s,  off);
            ss += __shfl_xor(ss, off);
        }
        const float mu   = s * (1.0f / D);
        const float var  = ss * (1.0f / D) - mu * mu;
        const float rstd = rsqrtf(var + EPS_LN);
        if (lane == 0) { mu_arr[n] = mu; rstd_arr[n] = rstd; }

        cs[0]+=x0.x; cs[1]+=x0.y; cs[2] +=x0.z; cs[3] +=x0.w;
        cs[4]+=x1.x; cs[5]+=x1.y; cs[6] +=x1.z; cs[7] +=x1.w;
        cs[8]+=x2.x; cs[9]+=x2.y; cs[10]+=x2.z; cs[11]+=x2.w;

        kvmin = fminf(kvmin, hmin4(kv4(x0, w0, c0, mu, rstd)));
        kvmin = fminf(kvmin, hmin4(kv4(x1, w1, c1, mu, rstd)));
        kvmin = fminf(kvmin, hmin4(kv4(x2, w2, c2, mu, rstd)));
    }

    #pragma unroll
    for (int off = 32; off; off >>= 1) kvmin = fminf(kvmin, __shfl_xor(kvmin, off));
    if (lane == 0) wvmin[wv] = kvmin;

    #pragma unroll
    for (int k = 0; k < 3; ++k)
        *(float4*)&lds[wv][4*lane + 256*k] = make_float4(cs[4*k], cs[4*k+1], cs[4*k+2], cs[4*k+3]);
    __syncthreads();

    float* colsum = ws + WS_COLSUM + (size_t)b * D;
    #pragma unroll
    for (int k = 0; k < 3; ++k) {
        const int c = tid + 256*k;
        atomicAdd(&colsum[c], lds[0][c] + lds[1][c] + lds[2][c] + lds[3][c]);
    }
    if (tid == 0) {
        float m = fminf(fminf(wvmin[0], wvmin[1]), fminf(wvmin[2], wvmin[3]));
        atomicMinFloat((unsigned int*)ws + WS_GMIN, m);
    }
}

// ---------------- K2: r[b] = scale * wk^T (wq q[b]) ----------------
__global__ __launch_bounds__(256) void k2_project(const float* __restrict__ wq,
                                                  const float* __restrict__ wk,
                                                  float* __restrict__ ws) {
    __shared__ float q[D];
    __shared__ float qq[D];
    const int tid  = threadIdx.x;
    const int lane = tid & 63;
    const int wv   = tid >> 6;
    const int b    = blockIdx.x;

    const float* colsum = ws + WS_COLSUM + (size_t)b * D;
    for (int c = tid; c < D; c += 256) q[c] = colsum[c] * (1.0f / N_ROWS);
    __syncthreads();

    // qq[i] = dot(q, wq[i,:]) — wave-parallel dot per output
    for (int t = 0; t < D / 4; ++t) {
        const int i = wv * (D / 4) + t;
        const float* row = wq + (size_t)i * D;
        float p = 0.0f;
        #pragma unroll
        for (int k = 0; k < 3; ++k) {
            const int c = 4*lane + 256*k;
            const float4 a = *(const float4*)(row + c);
            p += a.x*q[c] + a.y*q[c+1] + a.z*q[c+2] + a.w*q[c+3];
        }
        #pragma unroll
        for (int off = 32; off; off >>= 1) p += __shfl_xor(p, off);
        if (lane == 0) qq[i] = p;
    }
    __syncthreads();

    // r[j] = scale * sum_i qq[i] * wk[i,j]
    float a0 = 0.0f, a1 = 0.0f, a2 = 0.0f;
    for (int i = 0; i < D; ++i) {
        const float s = qq[i];
        const float* row = wk + (size_t)i * D;
        a0 += s * row[tid];
        a1 += s * row[tid + 256];
        a2 += s * row[tid + 512];
    }
    const float scale = rsqrtf((float)D);
    float* r = ws + WS_R + (size_t)b * D;
    r[tid]       = a0 * scale;
    r[tid + 256] = a1 * scale;
    r[tid + 512] = a2 * scale;
}

// ---------------- K3: logits[b,n] = r[b]·kv[b,n] (folded) ----------------
__global__ __launch_bounds__(256) void k3_logits(const float* __restrict__ x,
                                                 const float* __restrict__ lnw,
                                                 const float* __restrict__ lnb,
                                                 float* __restrict__ ws) {
    const int tid  = threadIdx.x;
    const int lane = tid & 63;
    const int wv   = tid >> 6;
    const int b    = blockIdx.x / BLOCKS_PER_B;
    const int chunk= blockIdx.x % BLOCKS_PER_B;
    const int n0   = chunk * ROWS_PER_BLOCK + wv * ROWS_PER_WAVE;

    const float4 w0 = *(const float4*)(lnw + 4*lane);
    const float4 w1 = *(const float4*)(lnw + 4*lane + 256);
    const float4 w2 = *(const float4*)(lnw + 4*lane + 512);
    const float4 c0 = *(const float4*)(lnb + 4*lane);
    const float4 c1 = *(const float4*)(lnb + 4*lane + 256);
    const float4 c2 = *(const float4*)(lnb + 4*lane + 512);

    const float* r = ws + WS_R + (size_t)b * D;
    const float4 r0 = *(const float4*)(r + 4*lane);
    const float4 r1 = *(const float4*)(r + 4*lane + 256);
    const float4 r2 = *(const float4*)(r + 4*lane + 512);

    // fold: logit = rstd*(Σ rw·x − mu·A) + C,  rw = r*w, A = Σ rw, C = Σ r·lnb
    const float4 rw0 = make_float4(r0.x*w0.x, r0.y*w0.y, r0.z*w0.z, r0.w*w0.w);
    const float4 rw1 = make_float4(r1.x*w1.x, r1.y*w1.y, r1.z*w1.z, r1.w*w1.w);
    const float4 rw2 = make_float4(r2.x*w2.x, r2.y*w2.y, r2.z*w2.z, r2.w*w2.w);
    float A = hsum4(rw0) + hsum4(rw1) + hsum4(rw2);
    float C = dot4(r0, c0) + dot4(r1, c1) + dot4(r2, c2);
    #pragma unroll
    for (int off = 32; off; off >>= 1) { A += __shfl_xor(A, off); C += __shfl_xor(C, off); }

    const float* mu_arr   = ws + WS_MU   + (size_t)b * N_ROWS;
    const float* rstd_arr = ws + WS_RSTD + (size_t)b * N_ROWS;
    float* logits = ws + WS_LOGITS + (size_t)b * N_ROWS;

    for (int i = 0; i < ROWS_PER_WAVE; ++i) {
        const int n = n0 + i;
        const float* row = x + ((size_t)b * N_ROWS + n) * D;
        const float4 x0 = *(const float4*)(row + 4*lane);
        const float4 x1 = *(const float4*)(row + 4*lane + 256);
        const float4 x2 = *(const float4*)(row + 4*lane + 512);
        float d = dot4(rw0, x0) + dot4(rw1, x1) + dot4(rw2, x2);
        #pragma unroll
        for (int off = 32; off; off >>= 1) d += __shfl_xor(d, off);
        if (lane == 0) {
            const float mu   = mu_arr[n];
            const float rstd = rstd_arr[n];
            logits[n] = rstd * (d - mu * A) + C;
        }
    }
}

// ---------------- K4: per-b softmax max + 1/sumexp ----------------
__global__ __launch_bounds__(256) void k4_softmax(float* __restrict__ ws) {
    const int b    = blockIdx.x;
    const int tid  = threadIdx.x;
    const int lane = tid & 63;
    const int wv   = tid >> 6;
    const float* logits = ws + WS_LOGITS + (size_t)b * N_ROWS;
    __shared__ float redmax[4];
    __shared__ float redsum[4];

    float m = -INFINITY;
    for (int n = tid; n < N_ROWS; n += 256) m = fmaxf(m, logits[n]);
    #pragma unroll
    for (int off = 32; off; off >>= 1) m = fmaxf(m, __shfl_xor(m, off));
    if (lane == 0) redmax[wv] = m;
    __syncthreads();
    m = fmaxf(fmaxf(redmax[0], redmax[1]), fmaxf(redmax[2], redmax[3]));

    float s = 0.0f;
    for (int n = tid; n < N_ROWS; n += 256) s += expf(logits[n] - m);
    #pragma unroll
    for (int off = 32; off; off >>= 1) s += __shfl_xor(s, off);
    if (lane == 0) redsum[wv] = s;
    __syncthreads();
    if (tid == 0) {
        const float total = redsum[0] + redsum[1] + redsum[2] + redsum[3];
        ws[WS_MXSUM + 2*b]     = m;
        ws[WS_MXSUM + 2*b + 1] = 1.0f / total;
    }
}

// ---------------- K5: out_acc[b,:] += attn[b,n] * (kv - gmin + eps)^2 ----------------
__global__ __launch_bounds__(256) void k5_accum(const float* __restrict__ x,
                                                const float* __restrict__ lnw,
                                                const float* __restrict__ lnb,
                                                float* __restrict__ ws) {
    __shared__ float lds[4][D];
    const int tid  = threadIdx.x;
    const int lane = tid & 63;
    const int wv   = tid >> 6;
    const int b    = blockIdx.x / BLOCKS_PER_B;
    const int chunk= blockIdx.x % BLOCKS_PER_B;
    const int n0   = chunk * ROWS_PER_BLOCK + wv * ROWS_PER_WAVE;

    const float4 w0 = *(const float4*)(lnw + 4*lane);
    const float4 w1 = *(const float4*)(lnw + 4*lane + 256);
    const float4 w2 = *(const float4*)(lnw + 4*lane + 512);
    const float4 c0 = *(const float4*)(lnb + 4*lane);
    const float4 c1 = *(const float4*)(lnb + 4*lane + 256);
    const float4 c2 = *(const float4*)(lnb + 4*lane + 512);

    const float gmin = __uint_as_float(((const unsigned int*)ws)[WS_GMIN]);
    const float mx   = ws[WS_MXSUM + 2*b];
    const float invs = ws[WS_MXSUM + 2*b + 1];
    const float* mu_arr   = ws + WS_MU   + (size_t)b * N_ROWS;
    const float* rstd_arr = ws + WS_RSTD + (size_t)b * N_ROWS;
    const float* logits   = ws + WS_LOGITS + (size_t)b * N_ROWS;

    float acc[12];
    #pragma unroll
    for (int i = 0; i < 12; ++i) acc[i] = 0.0f;

    for (int i = 0; i < ROWS_PER_WAVE; ++i) {
        const int n = n0 + i;
        const float* row = x + ((size_t)b * N_ROWS + n) * D;
        const float4 x0 = *(const float4*)(row + 4*lane);
        const float4 x1 = *(const float4*)(row + 4*lane + 256);
        const float4 x2 = *(const float4*)(row + 4*lane + 512);
        const float mu   = mu_arr[n];
        const float rstd = rstd_arr[n];
        const float wgt  = expf(logits[n] - mx) * invs;

        float4 kv;
        kv = kv4(x0, w0, c0, mu, rstd);
        { float t;
          t = kv.x - gmin + EPS_POOL; acc[0] += wgt * t * t;
          t = kv.y - gmin + EPS_POOL; acc[1] += wgt * t * t;
          t = kv.z - gmin + EPS_POOL; acc[2] += wgt * t * t;
          t = kv.w - gmin + EPS_POOL; acc[3] += wgt * t * t; }
        kv = kv4(x1, w1, c1, mu, rstd);
        { float t;
          t = kv.x - gmin + EPS_POOL; acc[4] += wgt * t * t;
          t = kv.y - gmin + EPS_POOL; acc[5] += wgt * t * t;
          t = kv.z - gmin + EPS_POOL; acc[6] += wgt * t * t;
          t = kv.w - gmin + EPS_POOL; acc[7] += wgt * t * t; }
        kv = kv4(x2, w2, c2, mu, rstd);
        { float t;
          t = kv.x - gmin + EPS_POOL; acc[8]  += wgt * t * t;
          t = kv.y - gmin + EPS_POOL; acc[9]  += wgt * t * t;
          t = kv.z - gmin + EPS_POOL; acc[10] += wgt * t * t;
          t = kv.w - gmin + EPS_POOL; acc[11] += wgt * t * t; }
    }

    #pragma unroll
    for (int k = 0; k < 3; ++k)
        *(float4*)&lds[wv][4*lane + 256*k] = make_float4(acc[4*k], acc[4*k+1], acc[4*k+2], acc[4*k+3]);
    __syncthreads();

    float* outacc = ws + WS_OUTACC + (size_t)b * D;
    #pragma unroll
    for (int k = 0; k < 3; ++k) {
        const int c = tid + 256*k;
        atomicAdd(&outacc[c], lds[0][c] + lds[1][c] + lds[2][c] + lds[3][c]);
    }
}

// ---------------- K6: out = sqrt(outacc) ----------------
__global__ __launch_bounds__(256) void k6_final(const float* __restrict__ ws,
                                                float* __restrict__ out) {
    const int i = blockIdx.x * 256 + threadIdx.x;
    if (i < B_SZ * D) out[i] = sqrtf(ws[WS_OUTACC + i]);
}

// ---------------- launch ----------------
extern "C" void kernel_launch(void* const* d_in, const int* in_sizes, int n_in,
                              void* d_out, int out_size, void* d_ws, size_t ws_size,
                              hipStream_t stream) {
    const float* x   = (const float*)d_in[0];
    const float* lnw = (const float*)d_in[1];
    const float* lnb = (const float*)d_in[2];
    const float* wq  = (const float*)d_in[3];
    const float* wk  = (const float*)d_in[4];
    float* ws  = (float*)d_ws;   // needs ~1.72 MB
    float* out = (float*)d_out;

    hipLaunchKernelGGL(k0_init,   dim3(96),        dim3(256), 0, stream, ws);
    hipLaunchKernelGGL(k1_stats,  dim3(NBLK_PASS), dim3(256), 0, stream, x, lnw, lnb, ws);
    hipLaunchKernelGGL(k2_project,dim3(B_SZ),      dim3(256), 0, stream, wq, wk, ws);
    hipLaunchKernelGGL(k3_logits, dim3(NBLK_PASS), dim3(256), 0, stream, x, lnw, lnb, ws);
    hipLaunchKernelGGL(k4_softmax,dim3(B_SZ),      dim3(256), 0, stream, ws);
    hipLaunchKernelGGL(k5_accum,  dim3(NBLK_PASS), dim3(256), 0, stream, x, lnw, lnb, ws);
    hipLaunchKernelGGL(k6_final,  dim3(48),        dim3(256), 0, stream, ws, out);
}

// Round 5
// 646.383 us; speedup vs baseline: 1.3257x; 1.3257x over previous
//
#include <hip/hip_runtime.h>
#include <math.h>

// ---------------- problem constants ----------------
#define B_SZ    16
#define N_ROWS  8192
#define D       768
#define EPS_LN  1e-6f
#define EPS_POOL 1e-6f
#define SCALE   0.03608439182435161f   // 768^-0.5

#define ROWS_PER_BLOCK 64
#define ROWS_PER_WAVE  16
#define BLOCKS_PER_B   (N_ROWS / ROWS_PER_BLOCK)   // 128
#define NBLK_PASS      (B_SZ * BLOCKS_PER_B)       // 2048

// ---------------- workspace layout (float offsets) ----------------
#define WS_COLSUM   0                       // B*D = 12288 (zeroed by k0)
#define WS_R        (WS_COLSUM + B_SZ*D)    // B*D = 12288 (zeroed by k0)
#define WS_QQ       (WS_R + B_SZ*D)         // B*D = 12288
#define WS_GMIN     (WS_QQ + B_SZ*D)        // 1 uint (init +inf), pad 32
#define WS_PART     (WS_GMIN + 32)          // NBLK_PASS * PART_STRIDE
#define PART_STRIDE 1544                    // [0]=m [1]=se [8..775]=acc1 [776..1543]=acc2
// total = 36896 + 2048*1544 = 3,199,008 floats = 12.8 MB

// ---------------- helpers ----------------
__device__ __forceinline__ void atomicMinFloat(unsigned int* addr, float val) {
    if (val >= 0.0f) atomicMin((int*)addr, __float_as_int(val));
    else             atomicMax(addr, __float_as_uint(val));
}

// ---------------- K0: init colsum, r, gmin ----------------
__global__ __launch_bounds__(256) void k0_init(float* __restrict__ ws) {
    int i = blockIdx.x * 256 + threadIdx.x;
    if (i < 2 * B_SZ * D) ws[i] = 0.0f;          // colsum + r (contiguous)
    if (i == 0) ((unsigned int*)ws)[WS_GMIN] = 0x7F800000u;  // +inf
}

// ---------------- KA: column sums of x (pass 1) ----------------
__global__ __launch_bounds__(256) void ka_colsum(const float* __restrict__ x,
                                                 float* __restrict__ ws) {
    __shared__ float lds[4][D];
    const int tid  = threadIdx.x;
    const int lane = tid & 63;
    const int wv   = tid >> 6;
    const int b    = blockIdx.x >> 7;          // /128
    const int chunk= blockIdx.x & 127;
    const int n0   = chunk * ROWS_PER_BLOCK + wv * ROWS_PER_WAVE;
    const float* base = x + ((size_t)b * N_ROWS + n0) * D + 4*lane;

    float cs[12];
    #pragma unroll
    for (int k = 0; k < 12; ++k) cs[k] = 0.0f;

    for (int i = 0; i < ROWS_PER_WAVE; ++i) {
        const float* row = base + (size_t)i * D;
        #pragma unroll
        for (int g = 0; g < 3; ++g) {
            const float4 v = *(const float4*)(row + 256*g);
            cs[4*g]   += v.x; cs[4*g+1] += v.y;
            cs[4*g+2] += v.z; cs[4*g+3] += v.w;
        }
    }
    #pragma unroll
    for (int g = 0; g < 3; ++g)
        *(float4*)&lds[wv][4*lane + 256*g] =
            make_float4(cs[4*g], cs[4*g+1], cs[4*g+2], cs[4*g+3]);
    __syncthreads();

    float* colsum = ws + WS_COLSUM + (size_t)b * D;
    #pragma unroll
    for (int k = 0; k < 3; ++k) {
        const int c = tid + 256*k;
        atomicAdd(&colsum[c], lds[0][c] + lds[1][c] + lds[2][c] + lds[3][c]);
    }
}

// ---------------- KB1: qq[b,i] = SCALE * dot(wq[i,:], q[b]) ----------------
// grid = 16 b * 12 i-chunks(64)
__global__ __launch_bounds__(256) void kb1_qq(const float* __restrict__ wq,
                                              float* __restrict__ ws) {
    __shared__ float q[D];
    const int tid  = threadIdx.x;
    const int lane = tid & 63;
    const int wv   = tid >> 6;
    const int b    = blockIdx.x / 12;
    const int ic   = blockIdx.x % 12;

    const float* colsum = ws + WS_COLSUM + (size_t)b * D;
    for (int c = tid; c < D; c += 256) q[c] = colsum[c] * (1.0f / N_ROWS);
    __syncthreads();

    for (int k = 0; k < 16; ++k) {
        const int i = ic * 64 + wv * 16 + k;
        const float* row = wq + (size_t)i * D + 4*lane;
        float p = 0.0f;
        #pragma unroll
        for (int g = 0; g < 3; ++g) {
            const float4 a = *(const float4*)(row + 256*g);
            const int c = 4*lane + 256*g;
            p += a.x*q[c] + a.y*q[c+1] + a.z*q[c+2] + a.w*q[c+3];
        }
        #pragma unroll
        for (int off = 32; off; off >>= 1) p += __shfl_xor(p, off);
        if (lane == 0) ws[WS_QQ + (size_t)b * D + i] = p * SCALE;
    }
}

// ---------------- KB2: r[b,j] += sum_i qq[b,i]*wk[i,j] ----------------
// grid = 3 j-tiles(256) * 16 i-chunks(48)
__global__ __launch_bounds__(256) void kb2_r(const float* __restrict__ wk,
                                             float* __restrict__ ws) {
    __shared__ float qs[16][48];
    const int tid = threadIdx.x;
    const int jt  = blockIdx.x / 16;
    const int ic  = blockIdx.x % 16;

    #pragma unroll
    for (int k = 0; k < 3; ++k) {
        const int v  = tid + 256*k;       // 0..767
        const int bb = v / 48, ii = v % 48;
        qs[bb][ii] = ws[WS_QQ + (size_t)bb * D + ic*48 + ii];
    }
    __syncthreads();

    float acc[16];
    #pragma unroll
    for (int bb = 0; bb < 16; ++bb) acc[bb] = 0.0f;

    const int j = jt * 256 + tid;
    for (int i = 0; i < 48; ++i) {
        const float wkv = wk[(size_t)(ic*48 + i) * D + j];
        #pragma unroll
        for (int bb = 0; bb < 16; ++bb) acc[bb] += qs[bb][i] * wkv;
    }
    #pragma unroll
    for (int bb = 0; bb < 16; ++bb)
        atomicAdd(&ws[WS_R + (size_t)bb * D + j], acc[bb]);
}

// ---------------- KC: fused logits + online softmax + GeM accumulate (pass 2) ----------------
__global__ __launch_bounds__(256) void kc_fused(const float* __restrict__ x,
                                                const float* __restrict__ lnw,
                                                const float* __restrict__ lnb,
                                                float* __restrict__ ws) {
    __shared__ float lds_acc[4][2*D];   // 24 KB: [wv][0..767]=acc1, [768..1535]=acc2
    __shared__ float lds_ms[4], lds_se[4], lds_min[4];
    const int tid  = threadIdx.x;
    const int lane = tid & 63;
    const int wv   = tid >> 6;
    const int b    = blockIdx.x >> 7;
    const int chunk= blockIdx.x & 127;
    const int n0   = chunk * ROWS_PER_BLOCK + wv * ROWS_PER_WAVE;

    // per-lane slices of lnw, lnb, r
    float w[12], cb[12], rw[12];
    float A = 0.0f, C = 0.0f;
    {
        const float* rb = ws + WS_R + (size_t)b * D + 4*lane;
        #pragma unroll
        for (int g = 0; g < 3; ++g) {
            const float4 vw = *(const float4*)(lnw + 4*lane + 256*g);
            const float4 vc = *(const float4*)(lnb + 4*lane + 256*g);
            const float4 vr = *(const float4*)(rb + 256*g);
            w[4*g]=vw.x; w[4*g+1]=vw.y; w[4*g+2]=vw.z; w[4*g+3]=vw.w;
            cb[4*g]=vc.x; cb[4*g+1]=vc.y; cb[4*g+2]=vc.z; cb[4*g+3]=vc.w;
            rw[4*g]  =vr.x*vw.x; rw[4*g+1]=vr.y*vw.y;
            rw[4*g+2]=vr.z*vw.z; rw[4*g+3]=vr.w*vw.w;
            C += vr.x*vc.x + vr.y*vc.y + vr.z*vc.z + vr.w*vc.w;
        }
        #pragma unroll
        for (int k = 0; k < 12; ++k) A += rw[k];
        #pragma unroll
        for (int off = 32; off; off >>= 1) {
            A += __shfl_xor(A, off); C += __shfl_xor(C, off);
        }
    }

    float m = -INFINITY, se = 0.0f, kvmin = INFINITY;
    float a1[12], a2[12];
    #pragma unroll
    for (int k = 0; k < 12; ++k) { a1[k] = 0.0f; a2[k] = 0.0f; }

    const float* base = x + ((size_t)b * N_ROWS + n0) * D + 4*lane;

    for (int i = 0; i < ROWS_PER_WAVE; ++i) {
        float xv[12];
        {
            const float* row = base + (size_t)i * D;
            #pragma unroll
            for (int g = 0; g < 3; ++g) {
                const float4 v = *(const float4*)(row + 256*g);
                xv[4*g]=v.x; xv[4*g+1]=v.y; xv[4*g+2]=v.z; xv[4*g+3]=v.w;
            }
        }
        float s = 0.0f, ss = 0.0f, dt = 0.0f;
        #pragma unroll
        for (int k = 0; k < 12; ++k) {
            s += xv[k]; ss += xv[k]*xv[k]; dt += rw[k]*xv[k];
        }
        #pragma unroll
        for (int off = 32; off; off >>= 1) {
            s  += __shfl_xor(s,  off);
            ss += __shfl_xor(ss, off);
            dt += __shfl_xor(dt, off);
        }
        const float mu   = s * (1.0f / D);
        const float var  = ss * (1.0f / D) - mu * mu;
        const float rstd = rsqrtf(var + EPS_LN);
        const float logit = rstd * (dt - mu * A) + C;

        // online softmax (wave-uniform branch; first iter zeroes accs via f=exp(-inf)=0)
        if (logit > m) {
            const float f = __expf(m - logit);
            se *= f;
            #pragma unroll
            for (int k = 0; k < 12; ++k) { a1[k] *= f; a2[k] *= f; }
            m = logit;
        }
        const float p = __expf(logit - m);
        se += p;

        #pragma unroll
        for (int k = 0; k < 12; ++k) {
            const float kv = (xv[k] - mu) * rstd * w[k] + cb[k];
            kvmin = fminf(kvmin, kv);
            const float u = p * kv;
            a1[k] += u;
            a2[k] += u * kv;
        }
    }

    if (lane == 0) lds_ms[wv] = m;
    __syncthreads();
    const float M = fmaxf(fmaxf(lds_ms[0], lds_ms[1]), fmaxf(lds_ms[2], lds_ms[3]));
    const float f = __expf(m - M);

    #pragma unroll
    for (int g = 0; g < 3; ++g) {
        *(float4*)&lds_acc[wv][4*lane + 256*g] =
            make_float4(a1[4*g]*f, a1[4*g+1]*f, a1[4*g+2]*f, a1[4*g+3]*f);
        *(float4*)&lds_acc[wv][D + 4*lane + 256*g] =
            make_float4(a2[4*g]*f, a2[4*g+1]*f, a2[4*g+2]*f, a2[4*g+3]*f);
    }
    #pragma unroll
    for (int off = 32; off; off >>= 1) kvmin = fminf(kvmin, __shfl_xor(kvmin, off));
    if (lane == 0) { lds_se[wv] = se * f; lds_min[wv] = kvmin; }
    __syncthreads();

    float* part = ws + WS_PART + (size_t)blockIdx.x * PART_STRIDE;
    if (tid == 0) {
        part[0] = M;
        part[1] = lds_se[0] + lds_se[1] + lds_se[2] + lds_se[3];
        atomicMinFloat((unsigned int*)ws + WS_GMIN,
                       fminf(fminf(lds_min[0], lds_min[1]), fminf(lds_min[2], lds_min[3])));
    }
    #pragma unroll
    for (int k = 0; k < 6; ++k) {
        const int idx = tid + 256*k;     // 0..1535
        part[8 + idx] = lds_acc[0][idx] + lds_acc[1][idx] + lds_acc[2][idx] + lds_acc[3][idx];
    }
}

// ---------------- KD: combine partials -> out ----------------
// grid = 16 b * 6 col-tiles(128), block 128
__global__ __launch_bounds__(128) void kd_combine(const float* __restrict__ ws,
                                                  float* __restrict__ out) {
    __shared__ float lds_f[128];
    __shared__ float red[4];
    const int tid  = threadIdx.x;          // 0..127
    const int lane = tid & 63;
    const int wv   = tid >> 6;
    const int b    = blockIdx.x / 6;
    const int jt   = blockIdx.x % 6;
    const float* pb = ws + WS_PART + (size_t)b * BLOCKS_PER_B * PART_STRIDE;

    const float mc = pb[(size_t)tid * PART_STRIDE + 0];
    const float sc = pb[(size_t)tid * PART_STRIDE + 1];

    float M = mc;
    #pragma unroll
    for (int off = 32; off; off >>= 1) M = fmaxf(M, __shfl_xor(M, off));
    if (lane == 0) red[wv] = M;
    __syncthreads();
    M = fmaxf(red[0], red[1]);

    const float fc = __expf(mc - M);
    float fs = fc * sc;
    #pragma unroll
    for (int off = 32; off; off >>= 1) fs += __shfl_xor(fs, off);
    if (lane == 0) red[2 + wv] = fs;
    lds_f[tid] = fc;
    __syncthreads();
    const float S = red[2] + red[3];
    const float G = __uint_as_float(((const unsigned int*)ws)[WS_GMIN]) - EPS_POOL;

    const int d = jt * 128 + tid;
    float A1 = 0.0f, A2 = 0.0f;
    for (int c = 0; c < BLOCKS_PER_B; ++c) {
        const float* p = pb + (size_t)c * PART_STRIDE;
        const float w = lds_f[c];
        A1 += w * p[8 + d];
        A2 += w * p[8 + D + d];
    }
    const float e1 = A1 / S;
    const float e2 = A2 / S;
    const float v  = e2 - 2.0f * G * e1 + G * G;
    out[(size_t)b * D + d] = sqrtf(fmaxf(v, 0.0f));
}

// ---------------- launch ----------------
extern "C" void kernel_launch(void* const* d_in, const int* in_sizes, int n_in,
                              void* d_out, int out_size, void* d_ws, size_t ws_size,
                              hipStream_t stream) {
    const float* x   = (const float*)d_in[0];
    const float* lnw = (const float*)d_in[1];
    const float* lnb = (const float*)d_in[2];
    const float* wq  = (const float*)d_in[3];
    const float* wk  = (const float*)d_in[4];
    float* ws  = (float*)d_ws;   // needs ~12.8 MB
    float* out = (float*)d_out;

    hipLaunchKernelGGL(k0_init,   dim3(96),        dim3(256), 0, stream, ws);
    hipLaunchKernelGGL(ka_colsum, dim3(NBLK_PASS), dim3(256), 0, stream, x, ws);
    hipLaunchKernelGGL(kb1_qq,    dim3(192),       dim3(256), 0, stream, wq, ws);
    hipLaunchKernelGGL(kb2_r,     dim3(48),        dim3(256), 0, stream, wk, ws);
    hipLaunchKernelGGL(kc_fused,  dim3(NBLK_PASS), dim3(256), 0, stream, x, lnw, lnb, ws);
    hipLaunchKernelGGL(kd_combine,dim3(96),        dim3(128), 0, stream, ws, out);
}